// Round 10
// baseline (311.209 us; speedup 1.0000x reference)
//
#include <hip/hip_runtime.h>
#include <cmath>

#define NB 8
#define NPTS 2048
#define NE (NB * NPTS)
#define THREADS 512
#define NPAIR 4   // packed row-pairs per wave -> 8 rows/wave, 64 rows/block
#define RPW (2 * NPAIR)

typedef float v2f __attribute__((ext_vector_type(2)));

#if defined(__has_builtin)
#if __has_builtin(__builtin_amdgcn_exp2f)
#define FAST_EXP2(x) __builtin_amdgcn_exp2f(x)
#else
#define FAST_EXP2(x) exp2f(x)
#endif
#if __has_builtin(__builtin_amdgcn_logf)
#define FAST_LOG2(x) __builtin_amdgcn_logf(x)
#else
#define FAST_LOG2(x) log2f(x)
#endif
#else
#define FAST_EXP2(x) exp2f(x)
#define FAST_LOG2(x) log2f(x)
#endif

// ---- DPP wave64 reductions (VALU pipe only; result valid at lane 63) ----
template<int CTRL>
__device__ __forceinline__ float dpp_f(float v) {
    return __int_as_float(__builtin_amdgcn_update_dpp(
        __float_as_int(v), __float_as_int(v), CTRL, 0xF, 0xF, false));
}
__device__ __forceinline__ float wred_max(float v) {
    v = fmaxf(v, dpp_f<0xB1>(v));
    v = fmaxf(v, dpp_f<0x4E>(v));
    v = fmaxf(v, dpp_f<0x141>(v));
    v = fmaxf(v, dpp_f<0x140>(v));
    v = fmaxf(v, dpp_f<0x142>(v));
    v = fmaxf(v, dpp_f<0x143>(v));
    return v;  // lane 63 correct
}
__device__ __forceinline__ float wred_sum(float v) {
    v += dpp_f<0xB1>(v);
    v += dpp_f<0x4E>(v);
    v += dpp_f<0x141>(v);
    v += dpp_f<0x140>(v);
    v += dpp_f<0x142>(v);
    v += dpp_f<0x143>(v);
    return v;  // lane 63 correct
}

// One Sinkhorn "phase": softmin_eps(C,h) for all rows of both sides, damped.
// LDS: xy4 = raw float4 copy of column points; hc2 = linear log2-domain
// column constant, with log(w_col) computed inline (no log_precompute).
// Inner loop: 8 rows/wave as 4 packed v2f pairs; per iter 1 ds_read_b128 +
// 1 ds_read_b64 covering 2 columns x 8 rows (4 packed ops + 1 exp per elem).
// Stabilizer m_est = prev LSE * eps-ratio; band-validated (s in (1e-30,1e34)
// => full fp32 precision), exact wave-local 2-pass redo otherwise.
// finalPhase: also emits per-block partial loss sums (deterministic).
__global__ __launch_bounds__(THREADS, 4) void sinkhorn_phase(
    const float* __restrict__ x, const float* __restrict__ y,
    const float* __restrict__ a, const float* __restrict__ b,
    const float* __restrict__ f_prev, const float* __restrict__ g_prev,
    float* __restrict__ f_next, float* __restrict__ g_next,
    float* __restrict__ Ls,          // [2][NB][NPTS] log2-domain LSE store
    float* __restrict__ partials,    // [gridDim] final-phase partial sums
    float eps, float inv_eps, float c_old, float c_new,
    float mscale, int initPhase, int finalPhase)
{
    __shared__ float4 xy4[NPTS / 2];   // 16 KB: {x_2k, y_2k, x_2k+1, y_2k+1}
    __shared__ float2 hc2[NPTS / 2];   // 8 KB: {hc_2k, hc_2k+1}
    __shared__ float pw[8];

    const int blk = blockIdx.x;
    const int side = blk >> 8;          // 256 blocks/side
    const int rblk = blk & 255;
    const int batch = rblk >> 5;        // 32 row-tiles (64 rows) per batch
    const int rowTile = rblk & 31;

    const float* rowPts; const float* colPts; const float* wcol; const float* wrow;
    const float* hpot; const float* ownPrev; float* outPot;
    if (side == 0) { rowPts=x; colPts=y; wcol=b; wrow=a; hpot=g_prev; ownPrev=f_prev; outPot=f_next; }
    else           { rowPts=y; colPts=x; wcol=a; wrow=b; hpot=f_prev; ownPrev=g_prev; outPot=g_next; }

    const float LOG2E = 1.4426950408889634f;
    const float LN2 = 0.69314718055994531f;

    // Stage xy: pure float4 copy (coalesced, no math).
    const float4* cp4 = ((const float4*)colPts) + (size_t)batch * (NPTS / 2);
    xy4[threadIdx.x]       = cp4[threadIdx.x];
    xy4[threadIdx.x + 512] = cp4[threadIdx.x + 512];

    // Stage hc linearly; log of the column weight computed inline.
    {
        const float2* cp2 = (const float2*)(colPts + (size_t)batch * NPTS * 2);
        const float* wl = wcol + (size_t)batch * NPTS;
        const float* pp = hpot + (size_t)batch * NPTS;
        float* hcs = (float*)hc2;
        #pragma unroll
        for (int k = 0; k < NPTS / THREADS; k++) {
            int j = threadIdx.x + k * THREADS;
            float2 p = cp2[j];
            float hp = initPhase ? 0.0f : pp[j] * inv_eps;
            hcs[j] = FAST_LOG2(wl[j]) +
                     (hp - 0.5f * inv_eps * fmaf(p.x, p.x, p.y * p.y)) * LOG2E;
        }
    }
    __syncthreads();

    const int lane = threadIdx.x & 63;
    const int wv = threadIdx.x >> 6;        // 8 waves/block
    const int row0 = rowTile * 64 + wv * RPW;
    const int gidx0 = batch * NPTS + row0;
    const float2* rp2 = (const float2*)(rowPts + (size_t)batch * NPTS * 2) + row0;
    const float* Lp = Ls + side * NE + gidx0;

    const float sc = inv_eps * LOG2E;
    v2f rxp[NPAIR], ryp[NPAIR], nmest[NPAIR], sp[NPAIR];
    #pragma unroll
    for (int p = 0; p < NPAIR; p++) {
        float2 p0 = rp2[2 * p];
        float2 p1 = rp2[2 * p + 1];
        rxp[p] = (v2f){p0.x * sc, p1.x * sc};
        ryp[p] = (v2f){p0.y * sc, p1.y * sc};
        float m0 = initPhase ? 0.0f : Lp[2 * p] * mscale;
        float m1 = initPhase ? 0.0f : Lp[2 * p + 1] * mscale;
        nmest[p] = (v2f){-m0, -m1};
        sp[p] = (v2f){0.0f, 0.0f};
    }

    // Fused pass: 16 iters; per iter 2 cols x 8 rows = 16 elements.
    #pragma unroll 4
    for (int it = 0; it < NPTS / 128; it++) {
        float4 v = xy4[(it << 6) + lane];
        float2 h = hc2[(it << 6) + lane];
        #pragma unroll
        for (int p = 0; p < NPAIR; p++) {
            v2f h0 = (v2f){h.x, h.x} + nmest[p];
            v2f h1 = (v2f){h.y, h.y} + nmest[p];
            v2f t0 = __builtin_elementwise_fma(rxp[p], (v2f){v.x, v.x},
                        __builtin_elementwise_fma(ryp[p], (v2f){v.y, v.y}, h0));
            v2f t1 = __builtin_elementwise_fma(rxp[p], (v2f){v.z, v.z},
                        __builtin_elementwise_fma(ryp[p], (v2f){v.w, v.w}, h1));
            sp[p] += (v2f){FAST_EXP2(t0.x), FAST_EXP2(t0.y)};
            sp[p] += (v2f){FAST_EXP2(t1.x), FAST_EXP2(t1.y)};
        }
    }
    float s[RPW];
    #pragma unroll
    for (int p = 0; p < NPAIR; p++) {
        s[2 * p]     = wred_sum(sp[p].x);
        s[2 * p + 1] = wred_sum(sp[p].y);
    }

    int bad = 0;
    if (lane == 63) {
        #pragma unroll
        for (int r = 0; r < RPW; r++)
            bad |= !(s[r] > 1e-30f && s[r] < 1e34f);
    }
    float mesc[RPW];
    #pragma unroll
    for (int p = 0; p < NPAIR; p++) {
        mesc[2 * p] = -nmest[p].x; mesc[2 * p + 1] = -nmest[p].y;
    }

    if (__any(bad)) {
        // Exact 2-pass redo (wave-local; no barrier needed).
        v2f mm[NPAIR];
        #pragma unroll
        for (int p = 0; p < NPAIR; p++) mm[p] = (v2f){-3.4e38f, -3.4e38f};
        #pragma unroll 4
        for (int it = 0; it < NPTS / 128; it++) {
            float4 v = xy4[(it << 6) + lane];
            float2 h = hc2[(it << 6) + lane];
            #pragma unroll
            for (int p = 0; p < NPAIR; p++) {
                v2f h0 = (v2f){h.x, h.x} + nmest[p];
                v2f h1 = (v2f){h.y, h.y} + nmest[p];
                v2f t0 = __builtin_elementwise_fma(rxp[p], (v2f){v.x, v.x},
                            __builtin_elementwise_fma(ryp[p], (v2f){v.y, v.y}, h0));
                v2f t1 = __builtin_elementwise_fma(rxp[p], (v2f){v.z, v.z},
                            __builtin_elementwise_fma(ryp[p], (v2f){v.w, v.w}, h1));
                mm[p] = __builtin_elementwise_max(mm[p],
                            __builtin_elementwise_max(t0, t1));
            }
        }
        float mmsc[RPW];
        #pragma unroll
        for (int p = 0; p < NPAIR; p++) {
            mmsc[2 * p] = mm[p].x; mmsc[2 * p + 1] = mm[p].y;
        }
        #pragma unroll
        for (int r = 0; r < RPW; r++) {
            mmsc[r] = wred_max(mmsc[r]);
            mmsc[r] = __shfl(mmsc[r], 63);   // broadcast shifted max
        }
        v2f mmb[NPAIR];
        #pragma unroll
        for (int p = 0; p < NPAIR; p++) {
            mmb[p] = (v2f){mmsc[2 * p], mmsc[2 * p + 1]};
            sp[p] = (v2f){0.0f, 0.0f};
        }
        #pragma unroll 4
        for (int it = 0; it < NPTS / 128; it++) {
            float4 v = xy4[(it << 6) + lane];
            float2 h = hc2[(it << 6) + lane];
            #pragma unroll
            for (int p = 0; p < NPAIR; p++) {
                v2f h0 = (v2f){h.x, h.x} + nmest[p] - mmb[p];
                v2f h1 = (v2f){h.y, h.y} + nmest[p] - mmb[p];
                v2f t0 = __builtin_elementwise_fma(rxp[p], (v2f){v.x, v.x},
                            __builtin_elementwise_fma(ryp[p], (v2f){v.y, v.y}, h0));
                v2f t1 = __builtin_elementwise_fma(rxp[p], (v2f){v.z, v.z},
                            __builtin_elementwise_fma(ryp[p], (v2f){v.w, v.w}, h1));
                sp[p] += (v2f){FAST_EXP2(t0.x), FAST_EXP2(t0.y)};
                sp[p] += (v2f){FAST_EXP2(t1.x), FAST_EXP2(t1.y)};
            }
        }
        #pragma unroll
        for (int p = 0; p < NPAIR; p++) {
            s[2 * p]     = wred_sum(sp[p].x);
            s[2 * p + 1] = wred_sum(sp[p].y);
            mesc[2 * p] += mmb[p].x;
            mesc[2 * p + 1] += mmb[p].y;
        }
    }

    if (lane == 63) {
        float part = 0.0f;
        #pragma unroll
        for (int r = 0; r < RPW; r++) {
            float2 p = rp2[r];
            float hr = -0.5f * sc * fmaf(p.x, p.x, p.y * p.y);
            float L = mesc[r] + FAST_LOG2(s[r]);          // log2-domain LSE
            float sm = -eps * LN2 * (hr + L);             // softmin value
            outPot[gidx0 + r] = c_old * ownPrev[gidx0 + r] + c_new * sm;
            Ls[side * NE + gidx0 + r] = L;                // estimator for next phase
            if (finalPhase) part += wrow[gidx0 + r] * sm;
        }
        if (finalPhase) pw[wv] = part;
    }
    if (finalPhase) {
        __syncthreads();
        if (threadIdx.x == 0) {
            float t = 0.0f;
            #pragma unroll
            for (int i = 0; i < 8; i++) t += pw[i];
            partials[blk] = t;
        }
    }
}

__global__ __launch_bounds__(512) void final_reduce(
    const float* __restrict__ partials, float* __restrict__ out)
{
    float v = partials[threadIdx.x];
    v += __shfl_xor(v, 32);
    v += __shfl_xor(v, 16);
    v += __shfl_xor(v, 8);
    v += __shfl_xor(v, 4);
    v += __shfl_xor(v, 2);
    v += __shfl_xor(v, 1);
    __shared__ float ws8[8];
    if ((threadIdx.x & 63) == 0) ws8[threadIdx.x >> 6] = v;
    __syncthreads();
    if (threadIdx.x == 0) {
        float t = 0.0f;
        #pragma unroll
        for (int i = 0; i < 8; i++) t += ws8[i];
        out[0] = t * (1.0f / NB);
    }
}

extern "C" void kernel_launch(void* const* d_in, const int* in_sizes, int n_in,
                              void* d_out, int out_size, void* d_ws, size_t ws_size,
                              hipStream_t stream)
{
    const float* a = (const float*)d_in[0];
    const float* x = (const float*)d_in[1];
    const float* b = (const float*)d_in[2];
    const float* y = (const float*)d_in[3];
    float* out = (float*)d_out;

    float* ws = (float*)d_ws;
    float* fA   = ws + 0 * NE;
    float* gA   = ws + 1 * NE;
    float* fB   = ws + 2 * NE;
    float* gB   = ws + 3 * NE;
    float* Ls   = ws + 4 * NE;      // 2*NE floats
    float* partials = ws + 6 * NE;  // 512 floats

    // eps annealing schedule (host-side, as in reference)
    double eps_list[32];
    int ne = 0;
    const double eps_final = 0.05 * 0.05;   // blur^p
    double eps = 2.0 * 2.0;                  // diameter^p
    while (eps > eps_final) { eps_list[ne++] = eps; eps *= 0.64; }  // scaling^p
    eps_list[ne++] = eps_final;              // ne == 18

    const float* fp = fA; const float* gp = gA;
    float* fn = fB; float* gn = gB;

    auto phase = [&](double e, double e_prev, float c_old, float c_new,
                     int init, int fin) {
        sinkhorn_phase<<<512, THREADS, 0, stream>>>(
            x, y, a, b, fp, gp, fn, gn, Ls, partials,
            (float)e, (float)(1.0 / e), c_old, c_new,
            (float)(e_prev / e), init, fin);
    };
    auto swapbuf = [&]() {
        const float* tf = fp; const float* tg = gp;
        fp = fn; gp = gn;
        fn = (float*)tf; gn = (float*)tg;
    };

    // init at eps0: h = log_b only; un-stabilized exponents are O(1) so
    // mest = 0 is in-band (band check still guards correctness).
    phase(eps_list[0], eps_list[0], 0.0f, 1.0f, 1, 0);
    swapbuf();
    // annealed damped iterations
    double e_prev = eps_list[0];
    for (int k = 0; k < ne; k++) {
        phase(eps_list[k], e_prev, 0.5f, 0.5f, 0, 0);
        e_prev = eps_list[k];
        swapbuf();
    }
    // final extrapolation at eps_final (no damping) + fused partial loss
    phase(eps_list[ne - 1], e_prev, 0.0f, 1.0f, 0, 1);

    final_reduce<<<1, 512, 0, stream>>>(partials, out);
}

// Round 11
// 279.231 us; speedup vs baseline: 1.1145x; 1.1145x over previous
//
#include <hip/hip_runtime.h>
#include <cmath>

#define NB 8
#define NPTS 2048
#define NE (NB * NPTS)
#define THREADS 512
#define NPAIR 2   // packed row-pairs per wave -> 4 rows/wave, 32 rows/block, 1024 blocks
#define RPW (2 * NPAIR)

typedef float v2f __attribute__((ext_vector_type(2)));

#if defined(__has_builtin)
#if __has_builtin(__builtin_amdgcn_exp2f)
#define FAST_EXP2(x) __builtin_amdgcn_exp2f(x)
#else
#define FAST_EXP2(x) exp2f(x)
#endif
#if __has_builtin(__builtin_amdgcn_logf)
#define FAST_LOG2(x) __builtin_amdgcn_logf(x)
#else
#define FAST_LOG2(x) log2f(x)
#endif
#else
#define FAST_EXP2(x) exp2f(x)
#define FAST_LOG2(x) log2f(x)
#endif

// ---- DPP wave64 reductions (VALU pipe only; result valid at lane 63) ----
template<int CTRL>
__device__ __forceinline__ float dpp_f(float v) {
    return __int_as_float(__builtin_amdgcn_update_dpp(
        __float_as_int(v), __float_as_int(v), CTRL, 0xF, 0xF, false));
}
__device__ __forceinline__ float wred_max(float v) {
    v = fmaxf(v, dpp_f<0xB1>(v));
    v = fmaxf(v, dpp_f<0x4E>(v));
    v = fmaxf(v, dpp_f<0x141>(v));
    v = fmaxf(v, dpp_f<0x140>(v));
    v = fmaxf(v, dpp_f<0x142>(v));
    v = fmaxf(v, dpp_f<0x143>(v));
    return v;  // lane 63 correct
}
__device__ __forceinline__ float wred_sum(float v) {
    v += dpp_f<0xB1>(v);
    v += dpp_f<0x4E>(v);
    v += dpp_f<0x141>(v);
    v += dpp_f<0x140>(v);
    v += dpp_f<0x142>(v);
    v += dpp_f<0x143>(v);
    return v;  // lane 63 correct
}

// One Sinkhorn "phase": softmin_eps(C,h) for all rows of both sides, damped.
// Grid: 1024 blocks x 512 thr = 32 waves/CU (R9's measured-optimal TLP).
// LDS: xy4 = raw float4 copy of column points; hc2 = linear log2-domain
// column constant. Steady-phase staging uses per-column invariants
// (base=log2 w, n2=-|p|^2/2) precomputed by the init phase -> 3 scalar
// loads + add + fma per column, no v_log.
// Inner loop: 4 rows/wave as 2 packed v2f pairs; per iter 1 ds_read_b128 +
// 1 ds_read_b64 covers 2 cols x 4 rows (2 packed ops + 1 exp per elem).
// Stabilizer m_est = prev LSE * eps-ratio; band-validated (s in (1e-30,1e34)
// => full fp32 precision), exact wave-local 2-pass redo otherwise.
// finalPhase: emits per-block partial loss sums (deterministic order).
__global__ __launch_bounds__(THREADS, 8) void sinkhorn_phase(
    const float* __restrict__ x, const float* __restrict__ y,
    const float* __restrict__ a, const float* __restrict__ b,
    const float* __restrict__ f_prev, const float* __restrict__ g_prev,
    float* __restrict__ f_next, float* __restrict__ g_next,
    float* __restrict__ Ls,          // [2][NB][NPTS] log2-domain LSE store
    float* __restrict__ colBase,     // [2][NB][NPTS] log2(w_col), init-written
    float* __restrict__ colN2,       // [2][NB][NPTS] -|p_col|^2/2, init-written
    float* __restrict__ partials,    // [1024] final-phase partial sums
    float eps, float inv_eps, float c_old, float c_new,
    float mscale, int initPhase, int finalPhase)
{
    __shared__ float4 xy4[NPTS / 2];   // 16 KB: {x_2k, y_2k, x_2k+1, y_2k+1}
    __shared__ float2 hc2[NPTS / 2];   // 8 KB: {hc_2k, hc_2k+1}
    __shared__ float pw[8];

    const int blk = blockIdx.x;
    const int side = blk >> 9;          // 512 blocks/side
    const int rblk = blk & 511;
    const int batch = rblk >> 6;        // 64 row-tiles (32 rows) per batch
    const int rowTile = rblk & 63;

    const float* rowPts; const float* colPts; const float* wcol; const float* wrow;
    const float* hpot; const float* ownPrev; float* outPot;
    if (side == 0) { rowPts=x; colPts=y; wcol=b; wrow=a; hpot=g_prev; ownPrev=f_prev; outPot=f_next; }
    else           { rowPts=y; colPts=x; wcol=a; wrow=b; hpot=f_prev; ownPrev=g_prev; outPot=g_next; }

    const float LOG2E = 1.4426950408889634f;
    const float LN2 = 0.69314718055994531f;
    const float sc = inv_eps * LOG2E;
    const int colOff = side * NE + batch * NPTS;

    // Stage xy: pure float4 copy (coalesced, no math).
    const float4* cp4 = ((const float4*)colPts) + (size_t)batch * (NPTS / 2);
    xy4[threadIdx.x]       = cp4[threadIdx.x];
    xy4[threadIdx.x + 512] = cp4[threadIdx.x + 512];

    // Stage hc linearly.
    {
        float* hcs = (float*)hc2;
        if (initPhase) {
            const float2* cp2 = (const float2*)(colPts + (size_t)batch * NPTS * 2);
            const float* wl = wcol + (size_t)batch * NPTS;
            #pragma unroll
            for (int k = 0; k < NPTS / THREADS; k++) {
                int j = threadIdx.x + k * THREADS;
                float2 p = cp2[j];
                float n2 = -0.5f * fmaf(p.x, p.x, p.y * p.y);
                float bse = FAST_LOG2(wl[j]);
                hcs[j] = fmaf(n2, sc, bse);
                if (rowTile == 0) {              // write invariants once
                    colBase[colOff + j] = bse;
                    colN2[colOff + j] = n2;
                }
            }
        } else {
            const float* pp = hpot + (size_t)batch * NPTS;
            const float* bs = colBase + colOff;
            const float* nn = colN2 + colOff;
            #pragma unroll
            for (int k = 0; k < NPTS / THREADS; k++) {
                int j = threadIdx.x + k * THREADS;
                hcs[j] = fmaf(pp[j] + nn[j], sc, bs[j]);
            }
        }
    }
    __syncthreads();

    const int lane = threadIdx.x & 63;
    const int wv = threadIdx.x >> 6;        // 8 waves/block
    const int row0 = rowTile * 32 + wv * RPW;
    const int gidx0 = batch * NPTS + row0;
    const float2* rp2 = (const float2*)(rowPts + (size_t)batch * NPTS * 2) + row0;
    const float* Lp = Ls + side * NE + gidx0;

    v2f rxp[NPAIR], ryp[NPAIR], nmest[NPAIR], sp[NPAIR];
    #pragma unroll
    for (int p = 0; p < NPAIR; p++) {
        float2 p0 = rp2[2 * p];
        float2 p1 = rp2[2 * p + 1];
        rxp[p] = (v2f){p0.x * sc, p1.x * sc};
        ryp[p] = (v2f){p0.y * sc, p1.y * sc};
        float m0 = initPhase ? 0.0f : Lp[2 * p] * mscale;
        float m1 = initPhase ? 0.0f : Lp[2 * p + 1] * mscale;
        nmest[p] = (v2f){-m0, -m1};
        sp[p] = (v2f){0.0f, 0.0f};
    }

    // Fused pass: 16 iters; per iter 2 cols x 4 rows = 8 elements.
    #pragma unroll 4
    for (int it = 0; it < NPTS / 128; it++) {
        float4 v = xy4[(it << 6) + lane];
        float2 h = hc2[(it << 6) + lane];
        #pragma unroll
        for (int p = 0; p < NPAIR; p++) {
            v2f h0 = (v2f){h.x, h.x} + nmest[p];
            v2f h1 = (v2f){h.y, h.y} + nmest[p];
            v2f t0 = __builtin_elementwise_fma(rxp[p], (v2f){v.x, v.x},
                        __builtin_elementwise_fma(ryp[p], (v2f){v.y, v.y}, h0));
            v2f t1 = __builtin_elementwise_fma(rxp[p], (v2f){v.z, v.z},
                        __builtin_elementwise_fma(ryp[p], (v2f){v.w, v.w}, h1));
            sp[p] += (v2f){FAST_EXP2(t0.x), FAST_EXP2(t0.y)};
            sp[p] += (v2f){FAST_EXP2(t1.x), FAST_EXP2(t1.y)};
        }
    }
    float s[RPW];
    #pragma unroll
    for (int p = 0; p < NPAIR; p++) {
        s[2 * p]     = wred_sum(sp[p].x);
        s[2 * p + 1] = wred_sum(sp[p].y);
    }

    int bad = 0;
    if (lane == 63) {
        #pragma unroll
        for (int r = 0; r < RPW; r++)
            bad |= !(s[r] > 1e-30f && s[r] < 1e34f);
    }
    float mesc[RPW];
    #pragma unroll
    for (int p = 0; p < NPAIR; p++) {
        mesc[2 * p] = -nmest[p].x; mesc[2 * p + 1] = -nmest[p].y;
    }

    if (__any(bad)) {
        // Exact 2-pass redo (wave-local; no barrier needed).
        v2f mm[NPAIR];
        #pragma unroll
        for (int p = 0; p < NPAIR; p++) mm[p] = (v2f){-3.4e38f, -3.4e38f};
        #pragma unroll 4
        for (int it = 0; it < NPTS / 128; it++) {
            float4 v = xy4[(it << 6) + lane];
            float2 h = hc2[(it << 6) + lane];
            #pragma unroll
            for (int p = 0; p < NPAIR; p++) {
                v2f h0 = (v2f){h.x, h.x} + nmest[p];
                v2f h1 = (v2f){h.y, h.y} + nmest[p];
                v2f t0 = __builtin_elementwise_fma(rxp[p], (v2f){v.x, v.x},
                            __builtin_elementwise_fma(ryp[p], (v2f){v.y, v.y}, h0));
                v2f t1 = __builtin_elementwise_fma(rxp[p], (v2f){v.z, v.z},
                            __builtin_elementwise_fma(ryp[p], (v2f){v.w, v.w}, h1));
                mm[p] = __builtin_elementwise_max(mm[p],
                            __builtin_elementwise_max(t0, t1));
            }
        }
        float mmsc[RPW];
        #pragma unroll
        for (int p = 0; p < NPAIR; p++) {
            mmsc[2 * p] = mm[p].x; mmsc[2 * p + 1] = mm[p].y;
        }
        #pragma unroll
        for (int r = 0; r < RPW; r++) {
            mmsc[r] = wred_max(mmsc[r]);
            mmsc[r] = __shfl(mmsc[r], 63);   // broadcast shifted max
        }
        v2f mmb[NPAIR];
        #pragma unroll
        for (int p = 0; p < NPAIR; p++) {
            mmb[p] = (v2f){mmsc[2 * p], mmsc[2 * p + 1]};
            sp[p] = (v2f){0.0f, 0.0f};
        }
        #pragma unroll 4
        for (int it = 0; it < NPTS / 128; it++) {
            float4 v = xy4[(it << 6) + lane];
            float2 h = hc2[(it << 6) + lane];
            #pragma unroll
            for (int p = 0; p < NPAIR; p++) {
                v2f h0 = (v2f){h.x, h.x} + nmest[p] - mmb[p];
                v2f h1 = (v2f){h.y, h.y} + nmest[p] - mmb[p];
                v2f t0 = __builtin_elementwise_fma(rxp[p], (v2f){v.x, v.x},
                            __builtin_elementwise_fma(ryp[p], (v2f){v.y, v.y}, h0));
                v2f t1 = __builtin_elementwise_fma(rxp[p], (v2f){v.z, v.z},
                            __builtin_elementwise_fma(ryp[p], (v2f){v.w, v.w}, h1));
                sp[p] += (v2f){FAST_EXP2(t0.x), FAST_EXP2(t0.y)};
                sp[p] += (v2f){FAST_EXP2(t1.x), FAST_EXP2(t1.y)};
            }
        }
        #pragma unroll
        for (int p = 0; p < NPAIR; p++) {
            s[2 * p]     = wred_sum(sp[p].x);
            s[2 * p + 1] = wred_sum(sp[p].y);
            mesc[2 * p] += mmb[p].x;
            mesc[2 * p + 1] += mmb[p].y;
        }
    }

    if (lane == 63) {
        float part = 0.0f;
        #pragma unroll
        for (int r = 0; r < RPW; r++) {
            float2 p = rp2[r];
            float hr = -0.5f * sc * fmaf(p.x, p.x, p.y * p.y);
            float L = mesc[r] + FAST_LOG2(s[r]);          // log2-domain LSE
            float sm = -eps * LN2 * (hr + L);             // softmin value
            outPot[gidx0 + r] = c_old * ownPrev[gidx0 + r] + c_new * sm;
            Ls[side * NE + gidx0 + r] = L;                // estimator for next phase
            if (finalPhase) part += wrow[gidx0 + r] * sm;
        }
        if (finalPhase) pw[wv] = part;
    }
    if (finalPhase) {
        __syncthreads();
        if (threadIdx.x == 0) {
            float t = 0.0f;
            #pragma unroll
            for (int i = 0; i < 8; i++) t += pw[i];
            partials[blk] = t;
        }
    }
}

__global__ __launch_bounds__(512) void final_reduce(
    const float* __restrict__ partials, float* __restrict__ out)
{
    float v = partials[threadIdx.x] + partials[threadIdx.x + 512];
    v += __shfl_xor(v, 32);
    v += __shfl_xor(v, 16);
    v += __shfl_xor(v, 8);
    v += __shfl_xor(v, 4);
    v += __shfl_xor(v, 2);
    v += __shfl_xor(v, 1);
    __shared__ float ws8[8];
    if ((threadIdx.x & 63) == 0) ws8[threadIdx.x >> 6] = v;
    __syncthreads();
    if (threadIdx.x == 0) {
        float t = 0.0f;
        #pragma unroll
        for (int i = 0; i < 8; i++) t += ws8[i];
        out[0] = t * (1.0f / NB);
    }
}

extern "C" void kernel_launch(void* const* d_in, const int* in_sizes, int n_in,
                              void* d_out, int out_size, void* d_ws, size_t ws_size,
                              hipStream_t stream)
{
    const float* a = (const float*)d_in[0];
    const float* x = (const float*)d_in[1];
    const float* b = (const float*)d_in[2];
    const float* y = (const float*)d_in[3];
    float* out = (float*)d_out;

    float* ws = (float*)d_ws;
    float* fA   = ws + 0 * NE;
    float* gA   = ws + 1 * NE;
    float* fB   = ws + 2 * NE;
    float* gB   = ws + 3 * NE;
    float* Ls   = ws + 4 * NE;      // 2*NE
    float* colBase = ws + 6 * NE;   // 2*NE
    float* colN2   = ws + 8 * NE;   // 2*NE
    float* partials = ws + 10 * NE; // 1024 floats

    // eps annealing schedule (host-side, as in reference)
    double eps_list[32];
    int ne = 0;
    const double eps_final = 0.05 * 0.05;   // blur^p
    double eps = 2.0 * 2.0;                  // diameter^p
    while (eps > eps_final) { eps_list[ne++] = eps; eps *= 0.64; }  // scaling^p
    eps_list[ne++] = eps_final;              // ne == 18

    const float* fp = fA; const float* gp = gA;
    float* fn = fB; float* gn = gB;

    auto phase = [&](double e, double e_prev, float c_old, float c_new,
                     int init, int fin) {
        sinkhorn_phase<<<1024, THREADS, 0, stream>>>(
            x, y, a, b, fp, gp, fn, gn, Ls, colBase, colN2, partials,
            (float)e, (float)(1.0 / e), c_old, c_new,
            (float)(e_prev / e), init, fin);
    };
    auto swapbuf = [&]() {
        const float* tf = fp; const float* tg = gp;
        fp = fn; gp = gn;
        fn = (float*)tf; gn = (float*)tg;
    };

    // init at eps0: h = log_b only; un-stabilized exponents are O(1) so
    // mest = 0 is in-band (band check still guards correctness). Also
    // writes the per-column invariants (log2 w, -|p|^2/2).
    phase(eps_list[0], eps_list[0], 0.0f, 1.0f, 1, 0);
    swapbuf();
    // annealed damped iterations
    double e_prev = eps_list[0];
    for (int k = 0; k < ne; k++) {
        phase(eps_list[k], e_prev, 0.5f, 0.5f, 0, 0);
        e_prev = eps_list[k];
        swapbuf();
    }
    // final extrapolation at eps_final (no damping) + fused partial loss
    phase(eps_list[ne - 1], e_prev, 0.0f, 1.0f, 0, 1);

    final_reduce<<<1, 512, 0, stream>>>(partials, out);
}